// Round 2
// baseline (5997.470 us; speedup 1.0000x reference)
//
#include <hip/hip_runtime.h>
#include <math.h>

typedef unsigned int u32;
typedef unsigned long long u64;

#define B_    8
#define C_    512
#define HW_   4096
#define NA    36864        // 4096*9 anchors per image
#define PRE_NMS  2000
#define POST_NMS 300

// output flat offsets (floats)
#define LOC_OFF   0
#define SC_OFF    1179648
#define ROIS_OFF  1769472
#define IDX_OFF   1779072
#define ANCH_OFF  1781472

// ---------------------------------------------------------------------------
// anchor generation: replicates numpy double math then float32 cast exactly
// ---------------------------------------------------------------------------
__device__ __forceinline__ float4 anchor_of(int px, int a) {
    const int py = px >> 6, pxx = px & 63;
    const double S[3] = {8.0, 16.0, 32.0};
    const double R[3] = {0.5, 1.0, 2.0};
    const double s = S[a % 3], r = R[a / 3];
    const double h = (16.0 * s) * sqrt(r);
    const double w = (16.0 * s) * sqrt(1.0 / r);
    const float bx1 = (float)(8.0 - w * 0.5);
    const float by1 = (float)(8.0 - h * 0.5);
    const float bx2 = (float)(8.0 + w * 0.5);
    const float by2 = (float)(8.0 + h * 0.5);
    const float sx = (float)(pxx * 16), sy = (float)(py * 16);
    return make_float4(__fadd_rn(sx, bx1), __fadd_rn(sy, by1),
                       __fadd_rn(sx, bx2), __fadd_rn(sy, by2));
}

// ---------------------------------------------------------------------------
// Kernel 1: 3x3 conv (pad 1) + bias + relu, fp32.
// grid (16 px-tiles, 8 k-tiles, 8 batch), block 256.
// tile: 64 k x 256 px (4 rows x 64 cols); per-thread 8k x 8px register tile.
// __launch_bounds__(256,4): cap VGPR at 128 so fr[3][10] + acc[8][8] stay
// register-resident (R1 showed VGPR=76 -> fr re-read from LDS per k-output).
// ---------------------------------------------------------------------------
__global__ __launch_bounds__(256, 4) void conv3x3_k(const float* __restrict__ feat,
                                                    const float* __restrict__ wgt,
                                                    const float* __restrict__ bias,
                                                    float* __restrict__ out) {
    const int b  = blockIdx.z, kt = blockIdx.y, pt = blockIdx.x;
    const int tid = threadIdx.x;
    const int k0 = kt * 64;
    const int y0 = pt * 4;                 // 4 output rows per tile
    __shared__ float sf[8][6][73];         // [c][row][col(-1..64)+1], pad to 73
    __shared__ float sw[64][96];           // [k][c*12 + pos], pos 0..8

    const int kg   = tid >> 5;             // 0..7 -> k = k0+kg*8..+7
    const int row  = (tid & 31) >> 3;      // 0..3
    const int col0 = (tid & 7) << 3;       // 0,8,..,56

    float acc[8][8];
#pragma unroll
    for (int i = 0; i < 8; ++i)
#pragma unroll
        for (int p = 0; p < 8; ++p) acc[i][p] = 0.f;

    const float* fb = feat + (size_t)b * (C_ * HW_);

    for (int c0 = 0; c0 < 512; c0 += 8) {
        __syncthreads();
        // stage feature tile: 8c x 6 rows x 66 cols (zero-padded halo)
        for (int e = tid; e < 8 * 6 * 66; e += 256) {
            int c = e / 396; int rem = e - c * 396;
            int rr = rem / 66; int cc = rem - rr * 66;
            int gy = y0 - 1 + rr, gx = cc - 1;
            float v = 0.f;
            if ((unsigned)gy < 64u && (unsigned)gx < 64u)
                v = fb[(c0 + c) * HW_ + (gy << 6) + gx];
            sf[c][rr][cc] = v;
        }
        // stage weights: 64k x 8c x 9 (coalesced global, conflict-free LDS)
        for (int e = tid; e < 64 * 72; e += 256) {
            int k = e / 72; int rem = e - k * 72;
            int c = rem / 9; int pos = rem - c * 9;
            sw[k][c * 12 + pos] = wgt[(size_t)(k0 + k) * 4608 + (c0 + c) * 9 + pos];
        }
        __syncthreads();

#pragma unroll 1
        for (int c = 0; c < 8; ++c) {
            float fr[3][10];
#pragma unroll
            for (int dy = 0; dy < 3; ++dy)
#pragma unroll
                for (int x = 0; x < 10; ++x)
                    fr[dy][x] = sf[c][row + dy][col0 + x];
#pragma unroll
            for (int i = 0; i < 8; ++i) {
                const float4 wA = *(const float4*)&sw[kg * 8 + i][c * 12];
                const float4 wB = *(const float4*)&sw[kg * 8 + i][c * 12 + 4];
                const float  w8 = sw[kg * 8 + i][c * 12 + 8];
                const float wv[9] = {wA.x, wA.y, wA.z, wA.w, wB.x, wB.y, wB.z, wB.w, w8};
#pragma unroll
                for (int dy = 0; dy < 3; ++dy)
#pragma unroll
                    for (int dx = 0; dx < 3; ++dx) {
                        const float wq = wv[dy * 3 + dx];
#pragma unroll
                        for (int p = 0; p < 8; ++p)
                            acc[i][p] = fmaf(fr[dy][p + dx], wq, acc[i][p]);
                    }
            }
        }
    }
    // epilogue: +bias, relu, store
#pragma unroll
    for (int i = 0; i < 8; ++i) {
        const int k = k0 + kg * 8 + i;
        const float bs = bias[k];
        float4 v0, v1;
        v0.x = fmaxf(__fadd_rn(acc[i][0], bs), 0.f);
        v0.y = fmaxf(__fadd_rn(acc[i][1], bs), 0.f);
        v0.z = fmaxf(__fadd_rn(acc[i][2], bs), 0.f);
        v0.w = fmaxf(__fadd_rn(acc[i][3], bs), 0.f);
        v1.x = fmaxf(__fadd_rn(acc[i][4], bs), 0.f);
        v1.y = fmaxf(__fadd_rn(acc[i][5], bs), 0.f);
        v1.z = fmaxf(__fadd_rn(acc[i][6], bs), 0.f);
        v1.w = fmaxf(__fadd_rn(acc[i][7], bs), 0.f);
        float* op = out + ((size_t)b * C_ + k) * HW_ + ((y0 + row) << 6) + col0;
        *(float4*)op = v0;
        *(float4*)(op + 4) = v1;
    }
}

// ---------------------------------------------------------------------------
// Kernel 2: 1x1 heads (36 loc + 18 cls), softmax-fg, decode, clip, min-size,
// sortable keys + rpn_loc/rpn_scores/anchors outputs.
// grid (16, 8=batch), block 256, one px per thread.
// __launch_bounds__(256,1): acc[56]+weight temps need ~140 VGPR; default
// budget (~76) would spill the accumulator every channel iteration.
// ---------------------------------------------------------------------------
__global__ __launch_bounds__(256, 1) void proj_k(const float* __restrict__ conv,
                                                 const float* __restrict__ loc_w,
                                                 const float* __restrict__ loc_b,
                                                 const float* __restrict__ cls_w,
                                                 const float* __restrict__ cls_b,
                                                 const int* __restrict__ ih,
                                                 const int* __restrict__ iw,
                                                 float* __restrict__ out,
                                                 float* __restrict__ boxes,
                                                 u64* __restrict__ keys) {
    const int b  = blockIdx.y;
    const int px = blockIdx.x * 256 + threadIdx.x;
    __shared__ float sw2[128][56];    // [c][o]  o: 0..35 loc, 36..53 cls

    float acc[56];
#pragma unroll
    for (int o = 0; o < 56; ++o) acc[o] = 0.f;

    for (int cc0 = 0; cc0 < 512; cc0 += 128) {
        __syncthreads();
        for (int e = threadIdx.x; e < 128 * 56; e += 256) {
            int c = e / 56, o = e - c * 56;
            float v = 0.f;
            if (o < 36)       v = loc_w[o * 512 + cc0 + c];
            else if (o < 54)  v = cls_w[(o - 36) * 512 + cc0 + c];
            sw2[c][o] = v;
        }
        __syncthreads();
        const float* cp = conv + ((size_t)b * C_ + cc0) * HW_ + px;
#pragma unroll 4
        for (int c = 0; c < 128; ++c) {
            const float a = cp[(size_t)c * HW_];
#pragma unroll
            for (int o4 = 0; o4 < 14; ++o4) {
                const float4 w4 = *(const float4*)&sw2[c][o4 * 4];
                acc[o4 * 4 + 0] = fmaf(a, w4.x, acc[o4 * 4 + 0]);
                acc[o4 * 4 + 1] = fmaf(a, w4.y, acc[o4 * 4 + 1]);
                acc[o4 * 4 + 2] = fmaf(a, w4.z, acc[o4 * 4 + 2]);
                acc[o4 * 4 + 3] = fmaf(a, w4.w, acc[o4 * 4 + 3]);
            }
        }
    }

    float locv[36], sv[18];
#pragma unroll
    for (int o = 0; o < 36; ++o) locv[o] = __fadd_rn(acc[o], loc_b[o]);
#pragma unroll
    for (int j = 0; j < 18; ++j) sv[j] = __fadd_rn(acc[36 + j], cls_b[j]);

    // rpn_loc (b, px*9+a, 4) and rpn_scores (b, px*9+a, 2)
    {
        float* lp = out + LOC_OFF + ((size_t)b * NA + (size_t)px * 9) * 4;
#pragma unroll
        for (int q = 0; q < 9; ++q)
            *(float4*)(lp + q * 4) = make_float4(locv[q*4], locv[q*4+1], locv[q*4+2], locv[q*4+3]);
        float* sp = out + SC_OFF + ((size_t)b * NA + (size_t)px * 9) * 2;
#pragma unroll
        for (int q = 0; q < 9; ++q)
            *(float2*)(sp + q * 2) = make_float2(sv[q*2], sv[q*2+1]);
    }

    const float fw = (float)iw[0], fh = (float)ih[0];
#pragma unroll
    for (int a = 0; a < 9; ++a) {
        const float4 an = anchor_of(px, a);
        // softmax fg (max-subtract, f32 ops like reference; exp via double->f32)
        const float s0 = sv[a * 2], s1 = sv[a * 2 + 1];
        const float m  = fmaxf(s0, s1);
        const float e0 = (float)exp((double)__fsub_rn(s0, m));
        const float e1 = (float)exp((double)__fsub_rn(s1, m));
        const float fg = __fdiv_rn(e1, __fadd_rn(e0, e1));
        // decode (mul/add separately, no FMA contraction — matches numpy)
        const float wa  = __fsub_rn(an.z, an.x), ha = __fsub_rn(an.w, an.y);
        const float cxa = __fadd_rn(an.x, __fmul_rn(0.5f, wa));
        const float cya = __fadd_rn(an.y, __fmul_rn(0.5f, ha));
        const float dx = locv[a*4], dy = locv[a*4+1], dw = locv[a*4+2], dh = locv[a*4+3];
        const float cx = __fadd_rn(__fmul_rn(dx, wa), cxa);
        const float cy = __fadd_rn(__fmul_rn(dy, ha), cya);
        const float ww = __fmul_rn((float)exp((double)dw), wa);
        const float hh = __fmul_rn((float)exp((double)dh), ha);
        float x1 = __fsub_rn(cx, __fmul_rn(0.5f, ww));
        float y1 = __fsub_rn(cy, __fmul_rn(0.5f, hh));
        float x2 = __fadd_rn(cx, __fmul_rn(0.5f, ww));
        float y2 = __fadd_rn(cy, __fmul_rn(0.5f, hh));
        x1 = fminf(fmaxf(x1, 0.f), fw);  y1 = fminf(fmaxf(y1, 0.f), fh);
        x2 = fminf(fmaxf(x2, 0.f), fw);  y2 = fminf(fmaxf(y2, 0.f), fh);

        const int n = px * 9 + a;
        *(float4*)(boxes + ((size_t)b * NA + n) * 4) = make_float4(x1, y1, x2, y2);

        const float ws_ = __fsub_rn(x2, x1), hs_ = __fsub_rn(y2, y1);
        const bool valid = (ws_ >= 16.f) && (hs_ >= 16.f);
        const u32 bits = __float_as_uint(fg);                  // fg >= 0 always
        const u32 key32 = valid ? (bits | 0x80000000u) : 0x007FFFFFu; // -inf key
        keys[(size_t)b * NA + n] = ((u64)key32 << 16) | (u64)(65535 - n);

        if (b == 0)
            *(float4*)(out + ANCH_OFF + (size_t)n * 4) = an;
    }
}

// ---------------------------------------------------------------------------
// Kernel 3: per-image exact top-2000 (radix select on unique 48-bit keys),
// bitonic sort, greedy NMS (single wave, register-resident boxes), compact.
// grid (8), block 256.
// ---------------------------------------------------------------------------
__global__ __launch_bounds__(256) void propose_k(const u64* __restrict__ keys_g,
                                                 const float* __restrict__ boxes_g,
                                                 float* __restrict__ out) {
    const int b = blockIdx.x;
    const u64* keys = keys_g + (size_t)b * NA;
    const float4* boxes = ((const float4*)boxes_g) + (size_t)b * NA;
    const int tid = threadIdx.x;

    __shared__ u64 skey[2048];
    __shared__ float4 sbox[2048];
    __shared__ u32 hist[256];
    __shared__ int scal[4];
    __shared__ unsigned char kb[2048];
    __shared__ short dst2[2048];
    __shared__ u32 keepm[64];

    // ---- radix select: exact 2000th-largest 48-bit key ----
    u64 prefix = 0; int rem = PRE_NMS;
    for (int shift = 40; shift >= 0; shift -= 8) {
        hist[tid] = 0;
        __syncthreads();
        const u64 ph = prefix >> (shift + 8);
        for (int e = tid; e < NA; e += 256) {
            u64 k = keys[e];
            if ((k >> (shift + 8)) == ph)
                atomicAdd(&hist[(u32)(k >> shift) & 255u], 1u);
        }
        __syncthreads();
        if (tid == 0) {
            int cum = 0, dsel = 0;
            for (int d = 255; d >= 0; --d) {
                int c = (int)hist[d];
                if (cum + c >= rem) { dsel = d; break; }
                cum += c;
            }
            scal[0] = dsel; scal[1] = cum;
        }
        __syncthreads();
        prefix |= ((u64)(u32)scal[0]) << shift;
        rem -= scal[1];
        __syncthreads();
    }
    const u64 kstar = prefix;

    // ---- collect the 2000 keys >= kstar ----
    if (tid == 0) scal[2] = 0;
    __syncthreads();
    for (int e = tid; e < NA; e += 256) {
        u64 k = keys[e];
        if (k >= kstar) { int p = atomicAdd(&scal[2], 1); if (p < 2048) skey[p] = k; }
    }
    __syncthreads();
    for (int r = scal[2] + tid; r < 2048; r += 256) skey[r] = 0;
    __syncthreads();

    // ---- bitonic sort 2048 u64 descending ----
    for (int kk = 2; kk <= 2048; kk <<= 1) {
        for (int j = kk >> 1; j > 0; j >>= 1) {
            for (int i = tid; i < 2048; i += 256) {
                int l = i ^ j;
                if (l > i) {
                    u64 a = skey[i], c = skey[l];
                    bool desc = ((i & kk) == 0);
                    if (desc ? (a < c) : (a > c)) { skey[i] = c; skey[l] = a; }
                }
            }
            __syncthreads();
        }
    }

    // ---- gather boxes + validity ----
    for (int r = tid; r < 2048; r += 256) {
        if (r < PRE_NMS) {
            u64 k = skey[r];
            int idx = 65535 - (int)(k & 0xFFFFu);
            if (idx >= NA) idx = NA - 1;          // defensive
            sbox[r] = boxes[idx];
            kb[r] = ((u32)(k >> 16) > 0x007FFFFFu) ? 1 : 0;
        } else { sbox[r] = make_float4(0,0,0,0); kb[r] = 0; }
    }
    __syncthreads();

    // ---- greedy NMS, single wave, forward-suppression form ----
    if (tid < 64) {
        const int lane = tid;
        u32 km = 0;
        float4 Bx[32]; float Ar[32];
#pragma unroll
        for (int t = 0; t < 32; ++t) {
            int r = t * 64 + lane;
            float4 v = sbox[r];
            Bx[t] = v;
            Ar[t] = __fmul_rn(__fsub_rn(v.z, v.x), __fsub_rn(v.w, v.y));
            km |= ((u32)kb[r]) << t;
        }
        for (int i = 0; i < PRE_NMS; ++i) {
            u32 m = (u32)__shfl((int)km, i & 63, 64);
            if (!((m >> (i >> 6)) & 1u)) continue;
            float4 bi = sbox[i];
            float ai = __fmul_rn(__fsub_rn(bi.z, bi.x), __fsub_rn(bi.w, bi.y));
#pragma unroll
            for (int t = 0; t < 32; ++t) {
                int r = t * 64 + lane;
                if (r <= i) continue;
                if (!((km >> t) & 1u)) continue;
                float lx = fmaxf(Bx[t].x, bi.x), ly = fmaxf(Bx[t].y, bi.y);
                float rx = fminf(Bx[t].z, bi.z), ry = fminf(Bx[t].w, bi.w);
                float wv = fmaxf(__fsub_rn(rx, lx), 0.f);
                float hv = fmaxf(__fsub_rn(ry, ly), 0.f);
                float inter = __fmul_rn(wv, hv);
                float den = __fadd_rn(__fsub_rn(__fadd_rn(Ar[t], ai), inter), 1e-9f);
                float iou = __fdiv_rn(inter, den);
                if (iou > 0.7f) km &= ~(1u << t);
            }
        }
        keepm[lane] = km;
    }
    __syncthreads();

    // ---- rank & compact ----
    if (tid == 0) {
        int cnt = 0;
        for (int r = 0; r < PRE_NMS; ++r) {
            if ((keepm[r & 63] >> (r >> 6)) & 1u) {
                dst2[r] = (cnt < POST_NMS) ? (short)cnt : (short)-1;
                ++cnt;
            } else dst2[r] = -1;
        }
        scal[3] = cnt;
    }
    __syncthreads();

    float* rois = out + ROIS_OFF + (size_t)b * POST_NMS * 4;
    for (int r = tid; r < PRE_NMS; r += 256) {
        int d = dst2[r];
        if (d >= 0) *(float4*)(rois + d * 4) = sbox[r];
    }
    int kc = scal[3]; if (kc > POST_NMS) kc = POST_NMS;
    for (int j = kc + tid; j < POST_NMS; j += 256)
        *(float4*)(rois + j * 4) = make_float4(0, 0, 0, 0);
    float* rip = out + IDX_OFF + (size_t)b * POST_NMS;
    for (int j = tid; j < POST_NMS; j += 256) rip[j] = (float)b;
}

// ---------------------------------------------------------------------------
extern "C" void kernel_launch(void* const* d_in, const int* in_sizes, int n_in,
                              void* d_out, int out_size, void* d_ws, size_t ws_size,
                              hipStream_t stream) {
    const float* feat    = (const float*)d_in[0];
    const float* conv1_w = (const float*)d_in[1];
    const float* conv1_b = (const float*)d_in[2];
    const float* cls_w   = (const float*)d_in[3];
    const float* cls_b   = (const float*)d_in[4];
    const float* loc_w   = (const float*)d_in[5];
    const float* loc_b   = (const float*)d_in[6];
    const int*   ih      = (const int*)d_in[7];
    const int*   iw      = (const int*)d_in[8];
    float* out = (float*)d_out;

    float* conv_ws  = (float*)d_ws;                               // 67,108,864 B
    float* boxes_ws = conv_ws + (size_t)B_ * C_ * HW_;            //  4,718,592 B
    u64*   keys_ws  = (u64*)(boxes_ws + (size_t)B_ * NA * 4);     //  2,359,296 B

    hipLaunchKernelGGL(conv3x3_k, dim3(16, 8, 8), dim3(256), 0, stream,
                       feat, conv1_w, conv1_b, conv_ws);
    hipLaunchKernelGGL(proj_k, dim3(16, 8), dim3(256), 0, stream,
                       conv_ws, loc_w, loc_b, cls_w, cls_b, ih, iw,
                       out, boxes_ws, keys_ws);
    hipLaunchKernelGGL(propose_k, dim3(8), dim3(256), 0, stream,
                       keys_ws, boxes_ws, out);
}

// Round 5
// 5184.766 us; speedup vs baseline: 1.1567x; 1.1567x over previous
//
#include <hip/hip_runtime.h>
#include <math.h>

typedef unsigned int u32;
typedef unsigned long long u64;

#define B_    8
#define C_    512
#define HW_   4096
#define NA    36864        // 4096*9 anchors per image
#define PRE_NMS  2000
#define POST_NMS 300

// output flat offsets (floats)
#define LOC_OFF   0
#define SC_OFF    1179648
#define ROIS_OFF  1769472
#define IDX_OFF   1779072
#define ANCH_OFF  1781472

// ---------------------------------------------------------------------------
// anchor generation: replicates numpy double math then float32 cast exactly
// ---------------------------------------------------------------------------
__device__ __forceinline__ float4 anchor_of(int px, int a) {
    const int py = px >> 6, pxx = px & 63;
    const double S[3] = {8.0, 16.0, 32.0};
    const double R[3] = {0.5, 1.0, 2.0};
    const double s = S[a % 3], r = R[a / 3];
    const double h = (16.0 * s) * sqrt(r);
    const double w = (16.0 * s) * sqrt(1.0 / r);
    const float bx1 = (float)(8.0 - w * 0.5);
    const float by1 = (float)(8.0 - h * 0.5);
    const float bx2 = (float)(8.0 + w * 0.5);
    const float by2 = (float)(8.0 + h * 0.5);
    const float sx = (float)(pxx * 16), sy = (float)(py * 16);
    return make_float4(__fadd_rn(sx, bx1), __fadd_rn(sy, by1),
                       __fadd_rn(sx, bx2), __fadd_rn(sy, by2));
}

// ---------------------------------------------------------------------------
// Kernel 1: 3x3 conv (pad 1) + bias + relu, fp32.
// grid (16 px-tiles, 16 k-tiles, 8 batch), block 256.
// tile: 32 k x 256 px; per-thread 4k x 8px (acc 32 + fr 30 ~= 75 VGPR by
// design -- R2 lesson: don't fight the allocator, fit its budget).
// Numerics validated in R3/R4 (rpn_loc passed).
// ---------------------------------------------------------------------------
__global__ __launch_bounds__(256) void conv3x3_k(const float* __restrict__ feat,
                                                 const float* __restrict__ wgt,
                                                 const float* __restrict__ bias,
                                                 float* __restrict__ out) {
    const int b  = blockIdx.z, kt = blockIdx.y, pt = blockIdx.x;
    const int tid = threadIdx.x;
    const int k0 = kt * 32;
    const int y0 = pt * 4;                 // 4 output rows per tile
    __shared__ float sf[8][6][76];         // [c][row][col(-1..64)], pad 76 (16B-aligned rows)
    __shared__ float sw[32][8][12];        // [k][c][pos 0..8 (+3 pad)]

    const int kg   = tid >> 5;             // 0..7 -> k = k0+kg*4+i
    const int row  = (tid & 31) >> 3;      // 0..3
    const int col0 = (tid & 7) << 3;       // 0,8,..,56

    float acc[4][8];
#pragma unroll
    for (int i = 0; i < 4; ++i)
#pragma unroll
        for (int p = 0; p < 8; ++p) acc[i][p] = 0.f;

    const float* fb = feat + (size_t)b * (C_ * HW_);

    for (int c0 = 0; c0 < 512; c0 += 8) {
        __syncthreads();
        // stage feature tile: 8c x 6 rows x 66 cols (zero-padded halo)
        for (int e = tid; e < 8 * 6 * 66; e += 256) {
            int c = e / 396; int rem = e - c * 396;
            int rr = rem / 66; int cc = rem - rr * 66;
            int gy = y0 - 1 + rr, gx = cc - 1;
            float v = 0.f;
            if ((unsigned)gy < 64u && (unsigned)gx < 64u)
                v = fb[(c0 + c) * HW_ + (gy << 6) + gx];
            sf[c][rr][cc] = v;
        }
        // stage weights: 32k x 8c x 9
        for (int e = tid; e < 32 * 72; e += 256) {
            int k = e / 72; int rem = e - k * 72;
            int c = rem / 9; int pos = rem - c * 9;
            sw[k][c][pos] = wgt[(size_t)(k0 + k) * 4608 + (c0 + c) * 9 + pos];
        }
        __syncthreads();

#pragma unroll
        for (int c = 0; c < 8; ++c) {
            float fr[3][10];
#pragma unroll
            for (int dy = 0; dy < 3; ++dy) {
                const float* rp = &sf[c][row + dy][col0];
                float4 aa = *(const float4*)rp;
                float4 bb = *(const float4*)(rp + 4);
                float2 c2 = *(const float2*)(rp + 8);
                fr[dy][0]=aa.x; fr[dy][1]=aa.y; fr[dy][2]=aa.z; fr[dy][3]=aa.w;
                fr[dy][4]=bb.x; fr[dy][5]=bb.y; fr[dy][6]=bb.z; fr[dy][7]=bb.w;
                fr[dy][8]=c2.x; fr[dy][9]=c2.y;
            }
#pragma unroll
            for (int i = 0; i < 4; ++i) {
                const float* wp = &sw[kg * 4 + i][c][0];
                const float4 wA = *(const float4*)wp;
                const float4 wB = *(const float4*)(wp + 4);
                const float  w8 = wp[8];
                const float wv[9] = {wA.x, wA.y, wA.z, wA.w, wB.x, wB.y, wB.z, wB.w, w8};
#pragma unroll
                for (int dy = 0; dy < 3; ++dy)
#pragma unroll
                    for (int dx = 0; dx < 3; ++dx) {
                        const float wq = wv[dy * 3 + dx];
#pragma unroll
                        for (int p = 0; p < 8; ++p)
                            acc[i][p] = fmaf(fr[dy][p + dx], wq, acc[i][p]);
                    }
            }
        }
    }
    // epilogue: +bias, relu, store
#pragma unroll
    for (int i = 0; i < 4; ++i) {
        const int k = k0 + kg * 4 + i;
        const float bs = bias[k];
        float4 v0, v1;
        v0.x = fmaxf(__fadd_rn(acc[i][0], bs), 0.f);
        v0.y = fmaxf(__fadd_rn(acc[i][1], bs), 0.f);
        v0.z = fmaxf(__fadd_rn(acc[i][2], bs), 0.f);
        v0.w = fmaxf(__fadd_rn(acc[i][3], bs), 0.f);
        v1.x = fmaxf(__fadd_rn(acc[i][4], bs), 0.f);
        v1.y = fmaxf(__fadd_rn(acc[i][5], bs), 0.f);
        v1.z = fmaxf(__fadd_rn(acc[i][6], bs), 0.f);
        v1.w = fmaxf(__fadd_rn(acc[i][7], bs), 0.f);
        float* op = out + ((size_t)b * C_ + k) * HW_ + ((y0 + row) << 6) + col0;
        *(float4*)op = v0;
        *(float4*)(op + 4) = v1;
    }
}

// ---------------------------------------------------------------------------
// Kernel 1b: transpose 1x1 head weights into [c][o].
// o: 0..35 loc, 36..53 cls, 54..55 ZERO PAD.
// R3/R4 BUG WAS HERE: o=54,55 read cls_w[18,19] out of bounds (garbage
// small weights) -> corrupted scores -> flipped NMS selection.
// ---------------------------------------------------------------------------
__global__ __launch_bounds__(256) void wprep_k(const float* __restrict__ loc_w,
                                               const float* __restrict__ cls_w,
                                               float* __restrict__ wt) {
    int idx = blockIdx.x * 256 + threadIdx.x;          // 112 blocks * 256 = 28672
    int c = idx / 56, o = idx - c * 56;
    float v = (o < 36) ? loc_w[o * 512 + c]
            : (o < 54) ? cls_w[(o - 36) * 512 + c]
            : 0.0f;                                    // pad, matches R1 staging
    wt[idx] = v;
}

// ---------------------------------------------------------------------------
// Kernel 2: 1x1 heads. block 256 = 4 o-groups x 64 px; acc[14]/thread (no
// spill possible). grid 512 = 8 b x 64 px-groups. Writes rpn_loc/rpn_scores.
// R3/R4 BUG WAS HERE: epilogue stored o=54,55 into px+1's score slots
// (cross-thread write race). Now skipped.
// ---------------------------------------------------------------------------
__global__ __launch_bounds__(256) void head_k(const float* __restrict__ conv,
                                              const float* __restrict__ wt,
                                              const float* __restrict__ loc_b,
                                              const float* __restrict__ cls_b,
                                              float* __restrict__ out) {
    const int blk = blockIdx.x;
    const int b = blk >> 6, px0 = (blk & 63) << 6;
    const int tid = threadIdx.x;
    const int og = tid >> 6, pxl = tid & 63;
    __shared__ float sW[64][64];   // [c][slot], slot = og*16 + q (16B-aligned groups)
    __shared__ float sF[64][72];   // [c][px], pad 72 (aligned, bank-spread)

    float acc[14];
#pragma unroll
    for (int q = 0; q < 14; ++q) acc[q] = 0.f;

    for (int cc0 = 0; cc0 < 512; cc0 += 64) {
        __syncthreads();
        for (int e = tid; e < 64 * 56; e += 256) {
            int c = e / 56, o = e - c * 56;
            int slot = (o >= 42) ? o + 6 : (o >= 28) ? o + 4 : (o >= 14) ? o + 2 : o;
            sW[c][slot] = wt[(cc0 + c) * 56 + o];
        }
        for (int e = tid; e < 1024; e += 256) {
            int c = e >> 4, p4 = (e & 15) << 2;
            *(float4*)&sF[c][p4] =
                *(const float4*)&conv[((size_t)b * C_ + cc0 + c) * HW_ + px0 + p4];
        }
        __syncthreads();
#pragma unroll 4
        for (int c = 0; c < 64; ++c) {
            const float a = sF[c][pxl];
            const float* wp = &sW[c][og * 16];
            float4 w0 = *(const float4*)wp;
            float4 w1 = *(const float4*)(wp + 4);
            float4 w2 = *(const float4*)(wp + 8);
            float2 w3 = *(const float2*)(wp + 12);
            acc[0]  = fmaf(a, w0.x, acc[0]);   acc[1]  = fmaf(a, w0.y, acc[1]);
            acc[2]  = fmaf(a, w0.z, acc[2]);   acc[3]  = fmaf(a, w0.w, acc[3]);
            acc[4]  = fmaf(a, w1.x, acc[4]);   acc[5]  = fmaf(a, w1.y, acc[5]);
            acc[6]  = fmaf(a, w1.z, acc[6]);   acc[7]  = fmaf(a, w1.w, acc[7]);
            acc[8]  = fmaf(a, w2.x, acc[8]);   acc[9]  = fmaf(a, w2.y, acc[9]);
            acc[10] = fmaf(a, w2.z, acc[10]);  acc[11] = fmaf(a, w2.w, acc[11]);
            acc[12] = fmaf(a, w3.x, acc[12]);  acc[13] = fmaf(a, w3.y, acc[13]);
        }
    }
    const int px = px0 + pxl;
    const size_t nb = (size_t)b * NA + (size_t)px * 9;
#pragma unroll
    for (int q = 0; q < 14; ++q) {
        int o = og * 14 + q;
        if (o >= 54) continue;               // pad outputs: DO NOT STORE
        float bsv = (o < 36) ? loc_b[o] : cls_b[o - 36];
        float v = __fadd_rn(acc[q], bsv);
        if (o < 36) out[LOC_OFF + nb * 4 + o] = v;
        else        out[SC_OFF + nb * 2 + (o - 36)] = v;
    }
}

// ---------------------------------------------------------------------------
// Kernel 3: per-anchor decode: softmax-fg, decode, clip, min-size, key, box.
// grid (8, 144), 1 thread = 1 anchor. Logic identical to R1's proj_k tail.
// ---------------------------------------------------------------------------
__global__ __launch_bounds__(256) void decode_k(const int* __restrict__ ih,
                                                const int* __restrict__ iw,
                                                float* __restrict__ out,
                                                float* __restrict__ boxes,
                                                u64* __restrict__ keys) {
    const int b = blockIdx.x;
    const int n = blockIdx.y * 256 + threadIdx.x;
    const float4 lv = *(const float4*)(out + LOC_OFF + ((size_t)b * NA + n) * 4);
    const float2 sc = *(const float2*)(out + SC_OFF + ((size_t)b * NA + n) * 2);
    const int px = n / 9, a = n - 9 * px;
    const float4 an = anchor_of(px, a);

    const float fw = (float)iw[0], fh = (float)ih[0];
    const float s0 = sc.x, s1 = sc.y;
    const float m  = fmaxf(s0, s1);
    const float e0 = (float)exp((double)__fsub_rn(s0, m));
    const float e1 = (float)exp((double)__fsub_rn(s1, m));
    const float fg = __fdiv_rn(e1, __fadd_rn(e0, e1));

    const float wa  = __fsub_rn(an.z, an.x), ha = __fsub_rn(an.w, an.y);
    const float cxa = __fadd_rn(an.x, __fmul_rn(0.5f, wa));
    const float cya = __fadd_rn(an.y, __fmul_rn(0.5f, ha));
    const float cx = __fadd_rn(__fmul_rn(lv.x, wa), cxa);
    const float cy = __fadd_rn(__fmul_rn(lv.y, ha), cya);
    const float ww = __fmul_rn((float)exp((double)lv.z), wa);
    const float hh = __fmul_rn((float)exp((double)lv.w), ha);
    float x1 = __fsub_rn(cx, __fmul_rn(0.5f, ww));
    float y1 = __fsub_rn(cy, __fmul_rn(0.5f, hh));
    float x2 = __fadd_rn(cx, __fmul_rn(0.5f, ww));
    float y2 = __fadd_rn(cy, __fmul_rn(0.5f, hh));
    x1 = fminf(fmaxf(x1, 0.f), fw);  y1 = fminf(fmaxf(y1, 0.f), fh);
    x2 = fminf(fmaxf(x2, 0.f), fw);  y2 = fminf(fmaxf(y2, 0.f), fh);

    *(float4*)(boxes + ((size_t)b * NA + n) * 4) = make_float4(x1, y1, x2, y2);

    const float ws_ = __fsub_rn(x2, x1), hs_ = __fsub_rn(y2, y1);
    const bool valid = (ws_ >= 16.f) && (hs_ >= 16.f);
    const u32 bits = __float_as_uint(fg);
    const u32 key32 = valid ? (bits | 0x80000000u) : 0x007FFFFFu;
    keys[(size_t)b * NA + n] = ((u64)key32 << 16) | (u64)(65535 - n);

    if (b == 0)
        *(float4*)(out + ANCH_OFF + (size_t)n * 4) = an;
}

// ---------------------------------------------------------------------------
// Kernel 4: per-image exact top-2000 (radix select on unique 48-bit keys),
// bitonic sort, greedy NMS (single wave, register-resident boxes), compact.
// grid (8), block 256.  VERBATIM from R1 (passed end-to-end).
// ---------------------------------------------------------------------------
__global__ __launch_bounds__(256) void propose_k(const u64* __restrict__ keys_g,
                                                 const float* __restrict__ boxes_g,
                                                 float* __restrict__ out) {
    const int b = blockIdx.x;
    const u64* keys = keys_g + (size_t)b * NA;
    const float4* boxes = ((const float4*)boxes_g) + (size_t)b * NA;
    const int tid = threadIdx.x;

    __shared__ u64 skey[2048];
    __shared__ float4 sbox[2048];
    __shared__ u32 hist[256];
    __shared__ int scal[4];
    __shared__ unsigned char kb[2048];
    __shared__ short dst2[2048];
    __shared__ u32 keepm[64];

    // ---- radix select: exact 2000th-largest 48-bit key ----
    u64 prefix = 0; int rem = PRE_NMS;
    for (int shift = 40; shift >= 0; shift -= 8) {
        hist[tid] = 0;
        __syncthreads();
        const u64 ph = prefix >> (shift + 8);
        for (int e = tid; e < NA; e += 256) {
            u64 k = keys[e];
            if ((k >> (shift + 8)) == ph)
                atomicAdd(&hist[(u32)(k >> shift) & 255u], 1u);
        }
        __syncthreads();
        if (tid == 0) {
            int cum = 0, dsel = 0;
            for (int d = 255; d >= 0; --d) {
                int c = (int)hist[d];
                if (cum + c >= rem) { dsel = d; break; }
                cum += c;
            }
            scal[0] = dsel; scal[1] = cum;
        }
        __syncthreads();
        prefix |= ((u64)(u32)scal[0]) << shift;
        rem -= scal[1];
        __syncthreads();
    }
    const u64 kstar = prefix;

    // ---- collect the 2000 keys >= kstar ----
    if (tid == 0) scal[2] = 0;
    __syncthreads();
    for (int e = tid; e < NA; e += 256) {
        u64 k = keys[e];
        if (k >= kstar) { int p = atomicAdd(&scal[2], 1); if (p < 2048) skey[p] = k; }
    }
    __syncthreads();
    for (int r = scal[2] + tid; r < 2048; r += 256) skey[r] = 0;
    __syncthreads();

    // ---- bitonic sort 2048 u64 descending ----
    for (int kk = 2; kk <= 2048; kk <<= 1) {
        for (int j = kk >> 1; j > 0; j >>= 1) {
            for (int i = tid; i < 2048; i += 256) {
                int l = i ^ j;
                if (l > i) {
                    u64 a = skey[i], c = skey[l];
                    bool desc = ((i & kk) == 0);
                    if (desc ? (a < c) : (a > c)) { skey[i] = c; skey[l] = a; }
                }
            }
            __syncthreads();
        }
    }

    // ---- gather boxes + validity ----
    for (int r = tid; r < 2048; r += 256) {
        if (r < PRE_NMS) {
            u64 k = skey[r];
            int idx = 65535 - (int)(k & 0xFFFFu);
            if (idx >= NA) idx = NA - 1;          // defensive
            sbox[r] = boxes[idx];
            kb[r] = ((u32)(k >> 16) > 0x007FFFFFu) ? 1 : 0;
        } else { sbox[r] = make_float4(0,0,0,0); kb[r] = 0; }
    }
    __syncthreads();

    // ---- greedy NMS, single wave, forward-suppression form ----
    if (tid < 64) {
        const int lane = tid;
        u32 km = 0;
        float4 Bx[32]; float Ar[32];
#pragma unroll
        for (int t = 0; t < 32; ++t) {
            int r = t * 64 + lane;
            float4 v = sbox[r];
            Bx[t] = v;
            Ar[t] = __fmul_rn(__fsub_rn(v.z, v.x), __fsub_rn(v.w, v.y));
            km |= ((u32)kb[r]) << t;
        }
        for (int i = 0; i < PRE_NMS; ++i) {
            u32 m = (u32)__shfl((int)km, i & 63, 64);
            if (!((m >> (i >> 6)) & 1u)) continue;
            float4 bi = sbox[i];
            float ai = __fmul_rn(__fsub_rn(bi.z, bi.x), __fsub_rn(bi.w, bi.y));
#pragma unroll
            for (int t = 0; t < 32; ++t) {
                int r = t * 64 + lane;
                if (r <= i) continue;
                if (!((km >> t) & 1u)) continue;
                float lx = fmaxf(Bx[t].x, bi.x), ly = fmaxf(Bx[t].y, bi.y);
                float rx = fminf(Bx[t].z, bi.z), ry = fminf(Bx[t].w, bi.w);
                float wv = fmaxf(__fsub_rn(rx, lx), 0.f);
                float hv = fmaxf(__fsub_rn(ry, ly), 0.f);
                float inter = __fmul_rn(wv, hv);
                float den = __fadd_rn(__fsub_rn(__fadd_rn(Ar[t], ai), inter), 1e-9f);
                float iou = __fdiv_rn(inter, den);
                if (iou > 0.7f) km &= ~(1u << t);
            }
        }
        keepm[lane] = km;
    }
    __syncthreads();

    // ---- rank & compact ----
    if (tid == 0) {
        int cnt = 0;
        for (int r = 0; r < PRE_NMS; ++r) {
            if ((keepm[r & 63] >> (r >> 6)) & 1u) {
                dst2[r] = (cnt < POST_NMS) ? (short)cnt : (short)-1;
                ++cnt;
            } else dst2[r] = -1;
        }
        scal[3] = cnt;
    }
    __syncthreads();

    float* rois = out + ROIS_OFF + (size_t)b * POST_NMS * 4;
    for (int r = tid; r < PRE_NMS; r += 256) {
        int d = dst2[r];
        if (d >= 0) *(float4*)(rois + d * 4) = sbox[r];
    }
    int kc = scal[3]; if (kc > POST_NMS) kc = POST_NMS;
    for (int j = kc + tid; j < POST_NMS; j += 256)
        *(float4*)(rois + j * 4) = make_float4(0, 0, 0, 0);
    float* rip = out + IDX_OFF + (size_t)b * POST_NMS;
    for (int j = tid; j < POST_NMS; j += 256) rip[j] = (float)b;
}

// ---------------------------------------------------------------------------
extern "C" void kernel_launch(void* const* d_in, const int* in_sizes, int n_in,
                              void* d_out, int out_size, void* d_ws, size_t ws_size,
                              hipStream_t stream) {
    const float* feat    = (const float*)d_in[0];
    const float* conv1_w = (const float*)d_in[1];
    const float* conv1_b = (const float*)d_in[2];
    const float* cls_w   = (const float*)d_in[3];
    const float* cls_b   = (const float*)d_in[4];
    const float* loc_w   = (const float*)d_in[5];
    const float* loc_b   = (const float*)d_in[6];
    const int*   ih      = (const int*)d_in[7];
    const int*   iw      = (const int*)d_in[8];
    float* out = (float*)d_out;

    // ws layout (no aliasing):
    //   conv_ws  : 8*512*4096 f32 = 67,108,864 B
    //   boxes_ws : 8*36864*4 f32  =  4,718,592 B
    //   keys_ws  : 8*36864 u64    =  2,359,296 B
    //   wt_ws    : 512*56 f32     =    114,688 B
    float* conv_ws  = (float*)d_ws;
    float* boxes_ws = conv_ws + (size_t)B_ * C_ * HW_;
    u64*   keys_ws  = (u64*)(boxes_ws + (size_t)B_ * NA * 4);
    float* wt_ws    = (float*)(keys_ws + (size_t)B_ * NA);

    hipLaunchKernelGGL(wprep_k, dim3(112), dim3(256), 0, stream, loc_w, cls_w, wt_ws);
    hipLaunchKernelGGL(conv3x3_k, dim3(16, 16, 8), dim3(256), 0, stream,
                       feat, conv1_w, conv1_b, conv_ws);
    hipLaunchKernelGGL(head_k, dim3(512), dim3(256), 0, stream,
                       conv_ws, wt_ws, loc_b, cls_b, out);
    hipLaunchKernelGGL(decode_k, dim3(8, 144), dim3(256), 0, stream,
                       ih, iw, out, boxes_ws, keys_ws);
    hipLaunchKernelGGL(propose_k, dim3(8), dim3(256), 0, stream,
                       keys_ws, boxes_ws, out);
}